// Round 1
// 370.325 us; speedup vs baseline: 1.1041x; 1.1041x over previous
//
#include <hip/hip_runtime.h>

#define NEDGES 20000
#define KMAX 16
#define NTRIP (NEDGES*KMAX)
#define EMB 128
#define INTERM 64
#define NSPH 7
#define UNITS 128
#define KSTEPS 256               // K = 8192 / 32

typedef __attribute__((ext_vector_type(8))) short short8;
typedef __attribute__((ext_vector_type(4))) float floatx4;
typedef __attribute__((ext_vector_type(2))) float v2f;

__device__ __forceinline__ unsigned bf16pair(float a, float b) {
    unsigned ua = __float_as_uint(a), ub = __float_as_uint(b);
    ua = (ua + 0x7fffu + ((ua >> 16) & 1u)) >> 16;
    ub = (ub + 0x7fffu + ((ub >> 16) & 1u)) & 0xffff0000u;
    return ua | ub;
}
__device__ __forceinline__ unsigned short bf16rne(float a) {
    unsigned u = __float_as_uint(a);
    return (unsigned short)((u + 0x7fffu + ((u >> 16) & 1u)) >> 16);
}
__device__ __forceinline__ v2f splat2(float f) { v2f r; r.x = f; r.y = f; return r; }

// prep: blocks [0, NTRIP/256) build the triplet->slot inverse table;
// blocks [NTRIP/256, +512) repack weight into bf16 MFMA B-fragment order.
// No memset needed: (id_reduce, Kidx) pairs are unique and cover all
// NEDGES*KMAX slots (problem construction), so inv is fully overwritten;
// fused_all additionally bounds-checks t.
__global__ __launch_bounds__(256)
void prep(const int* __restrict__ idr, const int* __restrict__ kix,
          int* __restrict__ inv, const float* __restrict__ w,
          uint4* __restrict__ w2f) {
    const int b = blockIdx.x, tid = threadIdx.x;
    if (b < NTRIP / 256) {
        int t = b * 256 + tid;
        int e = idr[t], k = kix[t];
        if ((unsigned)e < NEDGES && (unsigned)k < KMAX)
            inv[e * KMAX + k] = t;
    } else {
        // weight (emb, interm, o) fp32 -> bf16 MFMA B-fragment order.
        // uint4 idx = (nt*256 + ks)*64 + lane; elem j: k = ks*32 + (lane>>4)*8 + j,
        // o = nt*16 + (lane&15); k = i*128 + emb.
        int idx  = (b - NTRIP / 256) * 256 + tid;
        int lane = idx & 63;
        int ks   = (idx >> 6) & 255;
        int nt   = idx >> 14;
        int o  = nt * 16 + (lane & 15);
        int kb = ks * 32 + (lane >> 4) * 8;
        unsigned pk[4];
#pragma unroll
        for (int jj = 0; jj < 4; ++jj) {
            int k0 = kb + 2 * jj;
            int i0 = k0 >> 7, em0 = k0 & 127;
            int i1 = (k0 + 1) >> 7, em1 = (k0 + 1) & 127;
            float f0 = w[((size_t)em0 * INTERM + i0) * UNITS + o];
            float f1 = w[((size_t)em1 * INTERM + i1) * UNITS + o];
            pk[jj] = bf16pair(f0, f1);
        }
        w2f[idx] = make_uint4(pk[0], pk[1], pk[2], pk[3]);
    }
}

// fused_all: block = 32 edges x N=128 x full K. 512 threads (8 waves, wave = nt).
// Prologue fuses build_sumk: each thread (edge e = tid>>4, emb octet oct = tid&15)
// accumulates its sum_k slice skf[7][8] in fp32 registers directly from m/sph
// (m rows gathered via inv, coalesced float4 pairs). inv+sph broadcast tables
// live in LDS scratch aliased over the a_s double buffer (dead until main loop).
// Main loop: K iterated as 64 chunks of one interm i; A-frags built (packed-f32
// v_pk_fma math) into LDS double buffer, one barrier per chunk; w2f B-frags
// register-prefetched.
__global__ __launch_bounds__(512, 4)
void fused_all(const float* __restrict__ rbf, const float* __restrict__ sph,
               const float* __restrict__ m, const int* __restrict__ inv,
               const uint4* __restrict__ w2f, float* __restrict__ out) {
    __shared__ unsigned short rbf_s[32][528];   // 33792 B (16B-aligned rows)
    __shared__ uint4 a_s[2][8 * 65];            // 16640 B, row stride 65
    int*   inv_s = (int*)a_s;                   // prologue scratch: 2048 B
    float* sph_s = (float*)((char*)a_s + 2048); // prologue scratch: 14336 B

    const int tid = threadIdx.x;
    const size_t e0 = (size_t)blockIdx.x * 32;
    const int lane = tid & 63, wid = tid >> 6;   // wid = nt 0..7
    const int e = tid >> 4, oct = tid & 15;      // e 0..31
    const int mt = e >> 4;
    const int arow = mt * 4 + (oct >> 2);        // frag row within chunk (0..7)
    const int slot = (oct & 3) * 16 + (e & 15);  // lane within fragment

    // B-frag prefetch for chunk 0 — in flight across the whole prologue
    floatx4 acc[2] = {{0.f, 0.f, 0.f, 0.f}, {0.f, 0.f, 0.f, 0.f}};
    uint4 wf[4];
    const uint4* wbase = w2f + ((size_t)wid * KSTEPS) * 64 + lane;
#pragma unroll
    for (int ksl = 0; ksl < 4; ++ksl) wf[ksl] = wbase[(size_t)ksl * 64];

    // stage inv + sph into scratch, rbf tile -> bf16 LDS (rows padded to 8 per i)
    inv_s[tid] = inv[e0 * 16 + tid];
    for (int j = tid; j < 32 * 112; j += 512) sph_s[j] = sph[e0 * 112 + j];
    {
        const float4* rg = (const float4*)(rbf + e0 * 448);
        for (int f = tid; f < 3584; f += 512) {
            int ee = f / 112, idx = f - ee * 112;
            float4 v = rg[f];
            float vv[4] = {v.x, v.y, v.z, v.w};
            int rr = idx * 4;
#pragma unroll
            for (int x = 0; x < 4; ++x) {
                int r2 = rr + x, i = r2 / 7, s = r2 - i * 7;
                rbf_s[ee][i * 8 + s] = bf16rne(vv[x]);
            }
        }
    }
    __syncthreads();

    // fused build_sumk: skf[s][h] = sum_k sph[e][s][k] * m[inv[e][k]][oct*8+2h..+1]
    v2f skf[NSPH][4];
#pragma unroll
    for (int s = 0; s < NSPH; ++s)
#pragma unroll
        for (int h = 0; h < 4; ++h) skf[s][h] = splat2(0.f);
    {
        const float4* mrow = (const float4*)m;
        const int* ip = inv_s + e * 16;
        const float* sp = sph_s + e * 112;
#pragma unroll 2
        for (int k = 0; k < 16; ++k) {
            int t = ip[k];
            float4 v0 = make_float4(0.f, 0.f, 0.f, 0.f);
            float4 v1 = make_float4(0.f, 0.f, 0.f, 0.f);
            if ((unsigned)t < (unsigned)NTRIP) {
                const float4* tp = mrow + (size_t)t * 32 + oct * 2;
                v0 = tp[0];
                v1 = tp[1];
            }
            v2f mv[4];
            mv[0].x = v0.x; mv[0].y = v0.y;
            mv[1].x = v0.z; mv[1].y = v0.w;
            mv[2].x = v1.x; mv[2].y = v1.y;
            mv[3].x = v1.z; mv[3].y = v1.w;
#pragma unroll
            for (int s = 0; s < NSPH; ++s) {
                float cs = sp[s * 16 + k];
#pragma unroll
                for (int h = 0; h < 4; ++h)
                    skf[s][h] = __builtin_elementwise_fma(splat2(cs), mv[h], skf[s][h]);
            }
        }
    }
    __syncthreads();   // all scratch reads done; a_s reusable from here

    auto buildChunk = [&](int i, uint4* dst) {
        uint4 r4 = *(const uint4*)&rbf_s[e][i * 8];
        float rv[NSPH];
        rv[0] = __uint_as_float(r4.x << 16);
        rv[1] = __uint_as_float(r4.x & 0xffff0000u);
        rv[2] = __uint_as_float(r4.y << 16);
        rv[3] = __uint_as_float(r4.y & 0xffff0000u);
        rv[4] = __uint_as_float(r4.z << 16);
        rv[5] = __uint_as_float(r4.z & 0xffff0000u);
        rv[6] = __uint_as_float(r4.w << 16);
        v2f v[4];
#pragma unroll
        for (int h = 0; h < 4; ++h) v[h] = splat2(rv[0]) * skf[0][h];
#pragma unroll
        for (int s = 1; s < NSPH; ++s)
#pragma unroll
            for (int h = 0; h < 4; ++h)
                v[h] = __builtin_elementwise_fma(splat2(rv[s]), skf[s][h], v[h]);
        dst[arow * 65 + slot] = make_uint4(bf16pair(v[0].x, v[0].y), bf16pair(v[1].x, v[1].y),
                                           bf16pair(v[2].x, v[2].y), bf16pair(v[3].x, v[3].y));
    };

    buildChunk(0, a_s[0]);
    __syncthreads();

    for (int c = 0; c < 64; ++c) {
        const int cur = c & 1, nxt = cur ^ 1;
        if (c < 63) buildChunk(c + 1, a_s[nxt]);
#pragma unroll
        for (int ksl = 0; ksl < 4; ++ksl) {
            short8 a0 = __builtin_bit_cast(short8, a_s[cur][ksl * 65 + lane]);
            short8 a1 = __builtin_bit_cast(short8, a_s[cur][(4 + ksl) * 65 + lane]);
            short8 b  = __builtin_bit_cast(short8, wf[ksl]);
            acc[0] = __builtin_amdgcn_mfma_f32_16x16x32_bf16(a0, b, acc[0], 0, 0, 0);
            acc[1] = __builtin_amdgcn_mfma_f32_16x16x32_bf16(a1, b, acc[1], 0, 0, 0);
        }
        const int kn = (c < 63 ? c + 1 : 63) * 4;   // prefetch next chunk's B-frags
#pragma unroll
        for (int ksl = 0; ksl < 4; ++ksl) wf[ksl] = wbase[(size_t)(kn + ksl) * 64];
        __syncthreads();
    }

    // epilogue: C/D col = lane&15, row = (lane>>4)*4 + r
    const int col = lane & 15, r0 = (lane >> 4) * 4;
#pragma unroll
    for (int h = 0; h < 2; ++h) {
        size_t ebase = e0 + (size_t)h * 16 + r0;
#pragma unroll
        for (int r = 0; r < 4; ++r)
            out[(ebase + r) * UNITS + wid * 16 + col] = acc[h][r];
    }
}

extern "C" void kernel_launch(void* const* d_in, const int* in_sizes, int n_in,
                              void* d_out, int out_size, void* d_ws, size_t ws_size,
                              hipStream_t stream) {
    const float* rbf = (const float*)d_in[0];
    const float* sph = (const float*)d_in[1];
    const float* m   = (const float*)d_in[2];
    const float* w   = (const float*)d_in[3];
    const int*   idr = (const int*)d_in[4];
    const int*   kix = (const int*)d_in[5];
    float* out = (float*)d_out;

    // ws: inv (1.28 MB, pad to 0x140000) | w2f (2 MB)
    int*   inv = (int*)d_ws;
    uint4* w2f = (uint4*)((char*)d_ws + 0x140000);

    prep<<<NTRIP / 256 + 512, 256, 0, stream>>>(idr, kix, inv, w, w2f);
    fused_all<<<NEDGES / 32, 512, 0, stream>>>(rbf, sph, m, inv, w2f, out);
}